// Round 8
// baseline (3789.383 us; speedup 1.0000x reference)
//
#include <hip/hip_runtime.h>
#include <cstdint>
#include <cstddef>

// ---------------------------------------------------------------------------
// 2-layer LSTM (B=256, S=1024, V=H=256) + FC + log_softmax, MI355X/gfx950.
//
// Round 8: R7 topology (512 independent waves, frag-layout sentinel exchange)
// with the per-step serial chain thinned:
//  - weights pinned in VGPRs (waves_per_eu(1,1) + asm keep-alive; R7's
//    VGPR_Count=228 proved the compiler was rematerializing weight loads)
//  - zero per-step address math (pointer += 128KB; kt offsets = immediates)
//  - spin check on low dwords only (producer stores are 8B-atomic dwordx2)
//  - no own-chunk patching (same-wave republish is spin-safe)
//  - branch-free exp2-based sigmoid/tanh
//  - L0 x-fragments prefetched one step ahead
//
// Phases: pack_w x5 -> pack_x -> memset h1f/h2f 0xFF -> lstm_dual -> fc_lsm.
// Workspace ~405 MB: packed weights | xp (134MB) | h1f (134MB) | h2f (134MB)
// ---------------------------------------------------------------------------

typedef __attribute__((ext_vector_type(8))) short bf16x8;
typedef __attribute__((ext_vector_type(4))) float f32x4;
typedef unsigned long long ull;

#define DEVFN __device__ __forceinline__

constexpr unsigned SENT = 0xFFFFFFFFu;   // bf16 NaN pair: unreachable for tanh outputs

DEVFN unsigned short f2bf(float f) {
  union { float f; unsigned u; } v; v.f = f;
  unsigned r = v.u + 0x7FFFu + ((v.u >> 16) & 1u);   // RNE
  return (unsigned short)(r >> 16);
}
// branch-free fast sigmoid/tanh (exp2-based; saturate correctly at +-inf)
DEVFN float sigm(float x) {
  return __builtin_amdgcn_rcpf(1.f + exp2f(x * -1.442695041f));
}
DEVFN float tanh2(float x) {
  return 1.f - 2.f * __builtin_amdgcn_rcpf(1.f + exp2f(x * 2.885390082f));
}
DEVFN ull aload64(const ull* p) {
  return __hip_atomic_load(p, __ATOMIC_RELAXED, __HIP_MEMORY_SCOPE_AGENT);
}
DEVFN void astore64(ull* p, ull v) {
  __hip_atomic_store(p, v, __ATOMIC_RELAXED, __HIP_MEMORY_SCOPE_AGENT);
}
DEVFN bf16x8 fragu(ull a, ull b) {
  union { ull u[2]; bf16x8 f; } t; t.u[0] = a; t.u[1] = b; return t.f;
}
DEVFN bf16x8 frag4(uint4 u) { union { uint4 u; bf16x8 f; } t; t.u = u; return t.f; }

#define KEEP8(a0,a1,a2,a3,a4,a5,a6,a7) \
  asm volatile("" : "+v"(a0), "+v"(a1), "+v"(a2), "+v"(a3), \
                    "+v"(a4), "+v"(a5), "+v"(a6), "+v"(a7))

// --------------------------------------------------------------------------
// Pack W[col][k] (K=256) into B-fragment tiles:
//   dst[((nt*8+kt)*64+lane)*8 + j] = bf16( W[nt*16+(lane&15)][kt*32+(lane>>4)*8+j] )
// --------------------------------------------------------------------------
__global__ void pack_w(const float* __restrict__ w, unsigned short* __restrict__ dst) {
  int bid = blockIdx.x;           // nt*8 + kt
  int lane = threadIdx.x;
  int col = (bid >> 3) * 16 + (lane & 15);
  int k0  = (bid & 7) * 32 + (lane >> 4) * 8;
  const float* src = w + (size_t)col * 256 + k0;
  unsigned short* d = dst + ((size_t)bid * 64 + lane) * 8;
#pragma unroll
  for (int j = 0; j < 8; ++j) d[j] = f2bf(src[j]);
}

// --------------------------------------------------------------------------
// pack_x: x[b][t][v] f32 -> xp A-fragment layout bf16:
//   xp16B[((t*16+m)*8+kt)*64 + lane] = bf16( x[16m+(lane&15)][t][kt*32+(lane>>4)*8 + 0..7] )
// grid = 1024 blocks x 64 thr: bid = ((m*8+kt)*8 + tc), t in [tc*128, tc*128+128)
// --------------------------------------------------------------------------
__global__ void pack_x(const float* __restrict__ x, unsigned short* __restrict__ xp) {
  int bid = blockIdx.x, lane = threadIdx.x;
  int tc = bid & 7, kt = (bid >> 3) & 7, m = bid >> 6;
  int row = lane & 15, hi = lane >> 4;
  for (int t = tc * 128; t < tc * 128 + 128; ++t) {
    const float* s = x + ((size_t)(16 * m + row) * 1024 + t) * 256 + kt * 32 + hi * 8;
    float4 f0 = *(const float4*)s;
    float4 f1 = *(const float4*)(s + 4);
    uint4 o;
    o.x = f2bf(f0.x) | ((unsigned)f2bf(f0.y) << 16);
    o.y = f2bf(f0.z) | ((unsigned)f2bf(f0.w) << 16);
    o.z = f2bf(f1.x) | ((unsigned)f2bf(f1.y) << 16);
    o.w = f2bf(f1.z) | ((unsigned)f2bf(f1.w) << 16);
    *(uint4*)(xp + ((((size_t)t * 16 + m) * 8 + kt) * 64 + lane) * 8) = o;
  }
}

// --------------------------------------------------------------------------
// Dual-layer LSTM, independent waves. grid = 512 WGs x 64 thr.
// bid = w*32 + L*16 + m  (bid%8 == m%8: all 32 waves of an m-group share an
// XCD under the %8 placement heuristic — perf only).
// Wave (L,m,w): units [16w,16w+16) x 4 gates, rows [16m,16m+16).
// h exchange in MFMA A-fragment layout via sentinel-initialized buffers.
// --------------------------------------------------------------------------
__global__ __attribute__((amdgpu_flat_work_group_size(64, 64),
                          amdgpu_waves_per_eu(1, 1)))
void lstm_dual(
    const unsigned short* __restrict__ xp,
    const unsigned short* __restrict__ Wih0, const unsigned short* __restrict__ Whh0,
    const float* __restrict__ bih0, const float* __restrict__ bhh0,
    const unsigned short* __restrict__ Wih1, const unsigned short* __restrict__ Whh1,
    const float* __restrict__ bih1, const float* __restrict__ bhh1,
    unsigned short* __restrict__ h1f, unsigned short* __restrict__ h2f)
{
  __shared__ unsigned short tl[16][24];   // in-wave transpose tile (48B rows)
  const int lane = threadIdx.x;
  const int bid  = (int)blockIdx.x;
  const int m = bid & 15;
  const int L = (bid >> 4) & 1;
  const int w = bid >> 5;                 // unit-tile 0..15
  const int u = w * 16 + (lane & 15);
  const bool ownlane = (((lane >> 4) >> 1) == (w & 1));
  const int  mykt = w >> 1;               // frag kt this wave produces (half)

  const unsigned short* Wih = L ? Wih1 : Wih0;
  const unsigned short* Whh = L ? Whh1 : Whh0;
  const float* bihp = L ? bih1 : bih0;
  const float* bhhp = L ? bhh1 : bhh0;

  // register-resident weight B-fragments: nt = g*16 + w (pinned via KEEP8)
  bf16x8 bwih[4][8], bwhh[4][8];
#pragma unroll
  for (int g = 0; g < 4; ++g)
#pragma unroll
    for (int kt = 0; kt < 8; ++kt) {
      bwih[g][kt] = *(const bf16x8*)(Wih + ((((size_t)(g * 16 + w)) * 8 + kt) * 64 + lane) * 8);
      bwhh[g][kt] = *(const bf16x8*)(Whh + ((((size_t)(g * 16 + w)) * 8 + kt) * 64 + lane) * 8);
    }
#pragma unroll
  for (int g = 0; g < 4; ++g) {
    KEEP8(bwih[g][0], bwih[g][1], bwih[g][2], bwih[g][3],
          bwih[g][4], bwih[g][5], bwih[g][6], bwih[g][7]);
    KEEP8(bwhh[g][0], bwhh[g][1], bwhh[g][2], bwhh[g][3],
          bwhh[g][4], bwhh[g][5], bwhh[g][6], bwhh[g][7]);
  }

  float bias[4];
#pragma unroll
  for (int g = 0; g < 4; ++g) bias[g] = bihp[g * 256 + u] + bhhp[g * 256 + u];

  float c[4] = {0.f, 0.f, 0.f, 0.f};

  constexpr int TSTEP_U = 16384;   // ull per t   (16*8*64*2)
  constexpr int TSTEP_X = 8192;    // uint4 per t (16*8*64)

  if (!L) {
    // ================= layer 0 =================
    const ull* hrd  = (const ull*)h1f + m * 1024 + lane * 2;   // tile t-1, kt 0-3
    const ull* hrd2 = hrd + 512;                               // kt 4-7
    ull* hwr = (ull*)h1f + m * 1024 + mykt * 128 + lane * 2;   // publish, tile t
    const uint4* xq  = (const uint4*)xp + m * 512 + lane;      // x tile, kt 0-3
    const uint4* xq2 = xq + 256;                               // kt 4-7

    uint4 xpre[8];
#pragma unroll
    for (int kt = 0; kt < 4; ++kt) { xpre[kt] = xq[kt * 64]; xpre[4 + kt] = xq2[kt * 64]; }
    xq += TSTEP_X; xq2 += TSTEP_X;

    for (int t = 0; t < 1024; ++t) {
      ull hv[16];
      if (t > 0) {
#pragma unroll
        for (int kt = 0; kt < 4; ++kt) {
          hv[2*kt]     = aload64(hrd  + kt * 128);
          hv[2*kt + 1] = aload64(hrd  + kt * 128 + 1);
          hv[8 + 2*kt]     = aload64(hrd2 + kt * 128);
          hv[8 + 2*kt + 1] = aload64(hrd2 + kt * 128 + 1);
        }
      }

      f32x4 acc[4];
#pragma unroll
      for (int g = 0; g < 4; ++g) acc[g] = (f32x4){0.f, 0.f, 0.f, 0.f};
#pragma unroll
      for (int kt = 0; kt < 8; ++kt) {   // ih-MFMA (x prefetched last step)
        bf16x8 a = frag4(xpre[kt]);
#pragma unroll
        for (int g = 0; g < 4; ++g)
          acc[g] = __builtin_amdgcn_mfma_f32_16x16x32_bf16(a, bwih[g][kt], acc[g], 0, 0, 0);
      }

      if (t > 0) {
        int rounds = 0;
        while (true) {                   // sentinel spin (low-dword checks)
          bool bad = false;
#pragma unroll
          for (int i = 0; i < 16; ++i) bad = bad || ((unsigned)hv[i] == SENT);
          if (!__any(bad)) break;
          if (++rounds > 8) __builtin_amdgcn_s_sleep(1);
#pragma unroll
          for (int kt = 0; kt < 4; ++kt) {
            hv[2*kt]     = aload64(hrd  + kt * 128);
            hv[2*kt + 1] = aload64(hrd  + kt * 128 + 1);
            hv[8 + 2*kt]     = aload64(hrd2 + kt * 128);
            hv[8 + 2*kt + 1] = aload64(hrd2 + kt * 128 + 1);
          }
        }
#pragma unroll
        for (int kt = 0; kt < 8; ++kt) { // hh-MFMA
          bf16x8 a = fragu(hv[kt < 4 ? 2*kt : 2*kt], hv[kt < 4 ? 2*kt+1 : 2*kt+1]);
          // (kt 0-3 stored at hv[0..7], kt 4-7 at hv[8..15] in pairs)
#pragma unroll
          for (int g = 0; g < 4; ++g)
            acc[g] = __builtin_amdgcn_mfma_f32_16x16x32_bf16(a, bwhh[g][kt], acc[g], 0, 0, 0);
        }
        hrd += TSTEP_U; hrd2 += TSTEP_U;
      }

      float hq[4];
#pragma unroll
      for (int q = 0; q < 4; ++q) {
        float ia = acc[0][q] + bias[0];
        float fa = acc[1][q] + bias[1];
        float ga = acc[2][q] + bias[2];
        float oa = acc[3][q] + bias[3];
        c[q] = sigm(fa) * c[q] + sigm(ia) * tanh2(ga);
        hq[q] = sigm(oa) * tanh2(c[q]);
      }
#pragma unroll
      for (int q = 0; q < 4; ++q)
        tl[(lane >> 4) * 4 + q][lane & 15] = f2bf(hq[q]);
      uint4 nown = *(const uint4*)(&tl[lane & 15][((lane >> 4) & 1) * 8]);
      if (ownlane) {
        astore64(hwr,     ((ull)nown.y << 32) | nown.x);
        astore64(hwr + 1, ((ull)nown.w << 32) | nown.z);
      }
      hwr += TSTEP_U;

      if (t < 1023) {                    // prefetch x[t+1]
#pragma unroll
        for (int kt = 0; kt < 4; ++kt) { xpre[kt] = xq[kt * 64]; xpre[4 + kt] = xq2[kt * 64]; }
        xq += TSTEP_X; xq2 += TSTEP_X;
      }
    }
  } else {
    // ================= layer 1 =================
    const ull* prd  = (const ull*)h1f + m * 1024 + lane * 2;   // h1 tile t
    const ull* prd2 = prd + 512;
    const ull* hrd  = (const ull*)h2f + m * 1024 + lane * 2;   // h2 tile t-1
    const ull* hrd2 = hrd + 512;
    ull* hwr = (ull*)h2f + m * 1024 + mykt * 128 + lane * 2;

    for (int t = 0; t < 1024; ++t) {
      ull p1[16], hv[16];
#pragma unroll
      for (int kt = 0; kt < 4; ++kt) {   // issue p1 first (older on vmcnt)
        p1[2*kt]     = aload64(prd  + kt * 128);
        p1[2*kt + 1] = aload64(prd  + kt * 128 + 1);
        p1[8 + 2*kt]     = aload64(prd2 + kt * 128);
        p1[8 + 2*kt + 1] = aload64(prd2 + kt * 128 + 1);
      }
      if (t > 0) {
#pragma unroll
        for (int kt = 0; kt < 4; ++kt) {
          hv[2*kt]     = aload64(hrd  + kt * 128);
          hv[2*kt + 1] = aload64(hrd  + kt * 128 + 1);
          hv[8 + 2*kt]     = aload64(hrd2 + kt * 128);
          hv[8 + 2*kt + 1] = aload64(hrd2 + kt * 128 + 1);
        }
      }

      { // spin h1[t] (L0 runs ahead -> usually 1 round)
        int rounds = 0;
        while (true) {
          bool bad = false;
#pragma unroll
          for (int i = 0; i < 16; ++i) bad = bad || ((unsigned)p1[i] == SENT);
          if (!__any(bad)) break;
          if (++rounds > 8) __builtin_amdgcn_s_sleep(1);
#pragma unroll
          for (int kt = 0; kt < 4; ++kt) {
            p1[2*kt]     = aload64(prd  + kt * 128);
            p1[2*kt + 1] = aload64(prd  + kt * 128 + 1);
            p1[8 + 2*kt]     = aload64(prd2 + kt * 128);
            p1[8 + 2*kt + 1] = aload64(prd2 + kt * 128 + 1);
          }
        }
      }
      prd += TSTEP_U; prd2 += TSTEP_U;

      f32x4 acc[4];
#pragma unroll
      for (int g = 0; g < 4; ++g) acc[g] = (f32x4){0.f, 0.f, 0.f, 0.f};
#pragma unroll
      for (int kt = 0; kt < 8; ++kt) {   // ih-MFMA on h1[t]
        bf16x8 a = fragu(p1[2*kt], p1[2*kt + 1]);
#pragma unroll
        for (int g = 0; g < 4; ++g)
          acc[g] = __builtin_amdgcn_mfma_f32_16x16x32_bf16(a, bwih[g][kt], acc[g], 0, 0, 0);
      }

      if (t > 0) {
        int rounds = 0;
        while (true) {                   // spin h2[t-1]
          bool bad = false;
#pragma unroll
          for (int i = 0; i < 16; ++i) bad = bad || ((unsigned)hv[i] == SENT);
          if (!__any(bad)) break;
          if (++rounds > 8) __builtin_amdgcn_s_sleep(1);
#pragma unroll
          for (int kt = 0; kt < 4; ++kt) {
            hv[2*kt]     = aload64(hrd  + kt * 128);
            hv[2*kt + 1] = aload64(hrd  + kt * 128 + 1);
            hv[8 + 2*kt]     = aload64(hrd2 + kt * 128);
            hv[8 + 2*kt + 1] = aload64(hrd2 + kt * 128 + 1);
          }
        }
#pragma unroll
        for (int kt = 0; kt < 8; ++kt) { // hh-MFMA
          bf16x8 a = fragu(hv[2*kt], hv[2*kt + 1]);
#pragma unroll
          for (int g = 0; g < 4; ++g)
            acc[g] = __builtin_amdgcn_mfma_f32_16x16x32_bf16(a, bwhh[g][kt], acc[g], 0, 0, 0);
        }
        hrd += TSTEP_U; hrd2 += TSTEP_U;
      }

      float hq[4];
#pragma unroll
      for (int q = 0; q < 4; ++q) {
        float ia = acc[0][q] + bias[0];
        float fa = acc[1][q] + bias[1];
        float ga = acc[2][q] + bias[2];
        float oa = acc[3][q] + bias[3];
        c[q] = sigm(fa) * c[q] + sigm(ia) * tanh2(ga);
        hq[q] = sigm(oa) * tanh2(c[q]);
      }
#pragma unroll
      for (int q = 0; q < 4; ++q)
        tl[(lane >> 4) * 4 + q][lane & 15] = f2bf(hq[q]);
      uint4 nown = *(const uint4*)(&tl[lane & 15][((lane >> 4) & 1) * 8]);
      if (ownlane) {
        astore64(hwr,     ((ull)nown.y << 32) | nown.x);
        astore64(hwr + 1, ((ull)nown.w << 32) | nown.z);
      }
      hwr += TSTEP_U;
    }
  }
}

// --------------------------------------------------------------------------
// logits = h2 @ fc_w^T + fc_b; out = logits - logsumexp (rows of 256).
// h2 consumed directly in fragment layout. grid = 4096 x 256 thr.
// --------------------------------------------------------------------------
__global__ __launch_bounds__(256, 1) void fc_lsm(
    const unsigned short* __restrict__ h2f,
    const unsigned short* __restrict__ Bp,
    const float* __restrict__ fcb,
    float* __restrict__ out)
{
  const int tid = threadIdx.x;
  const int wid = tid >> 6, lane = tid & 63;
  const int t = blockIdx.x >> 2;
  const int mloc = (blockIdx.x & 3) * 4 + wid;   // m-group handled by this wave

  f32x4 acc[16];
#pragma unroll
  for (int nt = 0; nt < 16; ++nt) acc[nt] = (f32x4){0.f, 0.f, 0.f, 0.f};

#pragma unroll
  for (int kt = 0; kt < 8; ++kt) {
    bf16x8 a = *(const bf16x8*)(h2f + ((((size_t)t * 16 + mloc) * 8 + kt) * 64 + lane) * 8);
#pragma unroll
    for (int nt = 0; nt < 16; ++nt) {
      bf16x8 b = *(const bf16x8*)(Bp + (((size_t)nt * 8 + kt) * 64 + lane) * 8);
      acc[nt] = __builtin_amdgcn_mfma_f32_16x16x32_bf16(a, b, acc[nt], 0, 0, 0);
    }
  }
#pragma unroll
  for (int nt = 0; nt < 16; ++nt) {
    float bias = fcb[nt * 16 + (lane & 15)];
#pragma unroll
    for (int q = 0; q < 4; ++q) acc[nt][q] += bias;
  }

  float mx[4] = {-1e30f, -1e30f, -1e30f, -1e30f};
#pragma unroll
  for (int nt = 0; nt < 16; ++nt)
#pragma unroll
    for (int q = 0; q < 4; ++q) mx[q] = fmaxf(mx[q], acc[nt][q]);
#pragma unroll
  for (int d = 1; d < 16; d <<= 1)
#pragma unroll
    for (int q = 0; q < 4; ++q) mx[q] = fmaxf(mx[q], __shfl_xor(mx[q], d, 64));

  float sm[4] = {0.f, 0.f, 0.f, 0.f};
#pragma unroll
  for (int nt = 0; nt < 16; ++nt)
#pragma unroll
    for (int q = 0; q < 4; ++q) sm[q] += __expf(acc[nt][q] - mx[q]);
#pragma unroll
  for (int d = 1; d < 16; d <<= 1)
#pragma unroll
    for (int q = 0; q < 4; ++q) sm[q] += __shfl_xor(sm[q], d, 64);

  float lse[4];
#pragma unroll
  for (int q = 0; q < 4; ++q) lse[q] = mx[q] + __logf(sm[q]);

#pragma unroll
  for (int nt = 0; nt < 16; ++nt) {
#pragma unroll
    for (int q = 0; q < 4; ++q) {
      int b = mloc * 16 + (lane >> 4) * 4 + q;
      out[((size_t)b * 1024 + t) * 256 + nt * 16 + (lane & 15)] = acc[nt][q] - lse[q];
    }
  }
}

// Unambiguous marker if workspace is too small.
__global__ void fill_marker(float* out, size_t nvals) {
  size_t i = (size_t)blockIdx.x * blockDim.x + threadIdx.x;
  if (i < nvals) out[i] = -7777.0f;
}

// --------------------------------------------------------------------------
extern "C" void kernel_launch(void* const* d_in, const int* in_sizes, int n_in,
                              void* d_out, int out_size, void* d_ws, size_t ws_size,
                              hipStream_t stream)
{
  (void)in_sizes; (void)n_in;
  const float* x    = (const float*)d_in[0];
  const float* wih0 = (const float*)d_in[1];
  const float* whh0 = (const float*)d_in[2];
  const float* bih0 = (const float*)d_in[3];
  const float* bhh0 = (const float*)d_in[4];
  const float* wih1 = (const float*)d_in[5];
  const float* whh1 = (const float*)d_in[6];
  const float* bih1 = (const float*)d_in[7];
  const float* bhh1 = (const float*)d_in[8];
  const float* fcw  = (const float*)d_in[9];
  const float* fcb  = (const float*)d_in[10];
  float* out = (float*)d_out;

  // workspace layout (bytes)
  const size_t o_wp0i = 0;
  const size_t o_wp0h = o_wp0i + 524288;
  const size_t o_wp1i = o_wp0h + 524288;
  const size_t o_wp1h = o_wp1i + 524288;
  const size_t o_fcp  = o_wp1h + 524288;        // 131072
  const size_t o_xp   = o_fcp  + 131072;        // 134217728
  const size_t o_h1f  = o_xp   + 134217728;     // 134217728
  const size_t o_h2f  = o_h1f  + 134217728;     // 134217728
  const size_t need   = o_h2f  + 134217728;     // ~405 MB

  if (ws_size < need) {
    size_t nv = (size_t)out_size;
    fill_marker<<<(unsigned)((nv + 1023) / 1024), 1024, 0, stream>>>(out, nv);
    return;
  }

  char* ws = (char*)d_ws;
  unsigned short* wp0i = (unsigned short*)(ws + o_wp0i);
  unsigned short* wp0h = (unsigned short*)(ws + o_wp0h);
  unsigned short* wp1i = (unsigned short*)(ws + o_wp1i);
  unsigned short* wp1h = (unsigned short*)(ws + o_wp1h);
  unsigned short* fcp  = (unsigned short*)(ws + o_fcp);
  unsigned short* xp   = (unsigned short*)(ws + o_xp);
  unsigned short* h1f  = (unsigned short*)(ws + o_h1f);
  unsigned short* h2f  = (unsigned short*)(ws + o_h2f);

  pack_w<<<512, 64, 0, stream>>>(wih0, wp0i);
  pack_w<<<512, 64, 0, stream>>>(whh0, wp0h);
  pack_w<<<512, 64, 0, stream>>>(wih1, wp1i);
  pack_w<<<512, 64, 0, stream>>>(whh1, wp1h);
  pack_w<<<128, 64, 0, stream>>>(fcw,  fcp);
  pack_x<<<1024, 64, 0, stream>>>(x, xp);

  // sentinel-init frag buffers (0xFF bytes -> 0xFFFFFFFF dwords)
  hipMemsetAsync(h1f, 0xFF, 134217728, stream);
  hipMemsetAsync(h2f, 0xFF, 134217728, stream);

  lstm_dual<<<512, 64, 0, stream>>>(xp, wp0i, wp0h, bih0, bhh0,
                                    wp1i, wp1h, bih1, bhh1, h1f, h2f);

  fc_lsm<<<4096, 256, 0, stream>>>(h2f, fcp, fcb, out);
}